// Round 1
// baseline (542.231 us; speedup 1.0000x reference)
//
#include <hip/hip_runtime.h>

// Problem constants
#define E_ 158
#define F_ 2049
#define T_ 64
#define C_ 2
#define B_ 8
#define EF 323742           // E_*F_
#define EFT 20719488        // EF*T_ (per-batch element count, fits int32)
#define NOUT 165755904      // B_*EFT (fits int32)

// ---------------------------------------------------------------------------
// Kernel 1: proj[b,k] = xind[b,0]*W[k,0] + xind[b,1]*W[k,1] + bias[k]
// Written directly into the anchor region of d_out (anchor == proj flat).
// ---------------------------------------------------------------------------
__global__ __launch_bounds__(256) void proj_kernel(
    const float* __restrict__ xind, const float* __restrict__ W,
    const float* __restrict__ bias, float* __restrict__ anchor)
{
    unsigned int idx = blockIdx.x * 256u + threadIdx.x;     // over B_*EF
    if (idx >= (unsigned int)(B_ * EF)) return;
    unsigned int b = idx / (unsigned int)EF;
    unsigned int k = idx - b * (unsigned int)EF;
    float p = xind[b * 2 + 0] * W[2 * k + 0]
            + xind[b * 2 + 1] * W[2 * k + 1]
            + bias[k];
    anchor[idx] = p;
}

// ---------------------------------------------------------------------------
// Kernel 2: Rx[b,t] = dot(xs_flat[b, t*EF : (t+1)*EF], proj[b, :])
// One block per (b,t): 512 blocks x 256 threads, float2 loads (EF is even).
// ---------------------------------------------------------------------------
__global__ __launch_bounds__(256) void rx_kernel(
    const float* __restrict__ xs, const float* __restrict__ proj,
    float* __restrict__ Rx)
{
    const int bt = blockIdx.x;          // b*T_ + t
    const int b = bt >> 6;
    const int t = bt & 63;

    const float2* __restrict__ xp =
        (const float2*)(xs + (size_t)b * EFT + (size_t)t * EF);
    const float2* __restrict__ pp =
        (const float2*)(proj + (size_t)b * EF);

    float acc = 0.f;
    const int n2 = EF / 2;              // 161871
    for (int i = threadIdx.x; i < n2; i += 256) {
        float2 x = xp[i];
        float2 p = pp[i];
        acc += x.x * p.x + x.y * p.y;
    }
    // wave(64) butterfly reduce
    #pragma unroll
    for (int off = 32; off > 0; off >>= 1)
        acc += __shfl_down(acc, off, 64);

    __shared__ float sacc[4];
    const int lane = threadIdx.x & 63;
    const int w = threadIdx.x >> 6;
    if (lane == 0) sacc[w] = acc;
    __syncthreads();
    if (threadIdx.x == 0)
        Rx[bt] = sacc[0] + sacc[1] + sacc[2] + sacc[3];
}

// ---------------------------------------------------------------------------
// Kernel 3: out[i = b*EFT + k*T + t] = xs[i] * proj[b,k] * Rx[b,t]
// float4 over t (T=64 divisible by 4, so k constant within a float4).
// ---------------------------------------------------------------------------
__global__ __launch_bounds__(256) void gate_kernel(
    const float* __restrict__ xs, const float* __restrict__ proj,
    const float* __restrict__ Rx, float* __restrict__ out)
{
    unsigned int idx4 = blockIdx.x * 256u + threadIdx.x;    // float4 index
    const unsigned int N4 = NOUT / 4u;                      // 41438976
    if (idx4 >= N4) return;
    unsigned int i = idx4 * 4u;                             // element index
    unsigned int b = i / (unsigned int)EFT;
    unsigned int r = i - b * (unsigned int)EFT;
    unsigned int k = r >> 6;
    unsigned int t = r & 63u;

    float p = proj[(size_t)b * EF + k];
    const float* __restrict__ rx = Rx + b * T_;
    float4 x = ((const float4*)xs)[idx4];
    float4 o;
    o.x = x.x * p * rx[t + 0];
    o.y = x.y * p * rx[t + 1];
    o.z = x.z * p * rx[t + 2];
    o.w = x.w * p * rx[t + 3];
    ((float4*)out)[idx4] = o;
}

extern "C" void kernel_launch(void* const* d_in, const int* in_sizes, int n_in,
                              void* d_out, int out_size, void* d_ws, size_t ws_size,
                              hipStream_t stream)
{
    const float* xs   = (const float*)d_in[0];   // [B,E,F,T]
    const float* xind = (const float*)d_in[1];   // [B,C]
    const float* W    = (const float*)d_in[2];   // [E*F, C]
    const float* bias = (const float*)d_in[3];   // [E*F]

    float* out    = (float*)d_out;                       // [B,E,F,T] flat
    float* anchor = (float*)d_out + (size_t)NOUT;        // [B,F,E] flat == proj
    float* Rx     = (float*)d_ws;                        // [B,T] = 512 floats

    // 1) proj -> anchor region (serves as both output and scratch)
    {
        const int n = B_ * EF;                 // 2,589,936
        const int blocks = (n + 255) / 256;    // 10117
        proj_kernel<<<blocks, 256, 0, stream>>>(xind, W, bias, anchor);
    }
    // 2) Rx
    rx_kernel<<<B_ * T_, 256, 0, stream>>>(xs, anchor, Rx);
    // 3) gated output
    {
        const unsigned int blocks = (NOUT / 4 + 255) / 256;  // 161871
        gate_kernel<<<blocks, 256, 0, stream>>>(xs, anchor, Rx, out);
    }
}

// Round 2
// 416.453 us; speedup vs baseline: 1.3020x; 1.3020x over previous
//
#include <hip/hip_runtime.h>

// Problem constants
#define E_ 158
#define F_ 2049
#define T_ 64
#define C_ 2
#define B_ 8
#define EF 323742           // E_*F_
#define EF2 161871          // EF/2 (float2 units per t-chunk)
#define EFT 20719488        // EF*T_ (per-batch element count)
#define NOUT 165755904      // B_*EFT
#define NSEG 16
#define SEG2 10117          // ceil(EF2/NSEG); last segment = EF2 - 15*SEG2 = 10116

// ---------------------------------------------------------------------------
// Kernel 1: proj[b,k] = xind[b,0]*W[k,0] + xind[b,1]*W[k,1] + bias[k]
// Written directly into the anchor region of d_out (anchor == proj flat).
// ---------------------------------------------------------------------------
__global__ __launch_bounds__(256) void proj_kernel(
    const float* __restrict__ xind, const float* __restrict__ W,
    const float* __restrict__ bias, float* __restrict__ anchor)
{
    unsigned int idx = blockIdx.x * 256u + threadIdx.x;     // over B_*EF
    if (idx >= (unsigned int)(B_ * EF)) return;
    unsigned int b = idx / (unsigned int)EF;
    unsigned int k = idx - b * (unsigned int)EF;
    float p = xind[b * 2 + 0] * W[2 * k + 0]
            + xind[b * 2 + 1] * W[2 * k + 1]
            + bias[k];
    anchor[idx] = p;
}

// ---------------------------------------------------------------------------
// Kernel 2 (per batch b): partial dot products.
// Block (t,s): sums xs_flat[b, t*EF + s-th segment] . proj[b, same range]
// into part[t*NSEG + s].  Grid = 64*16 = 1024 blocks.
// ---------------------------------------------------------------------------
__global__ __launch_bounds__(256) void rx_part_kernel(
    const float* __restrict__ xs, const float* __restrict__ proj,
    float* __restrict__ part, int b)
{
    const int t = blockIdx.x >> 4;
    const int s = blockIdx.x & 15;
    const int len2 = (s == NSEG - 1) ? (EF2 - (NSEG - 1) * SEG2) : SEG2;

    const float2* __restrict__ xp =
        (const float2*)(xs + (size_t)b * EFT) + (size_t)t * EF2 + (size_t)s * SEG2;
    const float2* __restrict__ pp =
        (const float2*)(proj + (size_t)b * EF) + (size_t)s * SEG2;

    float acc = 0.f;
    #pragma unroll 4
    for (int i = threadIdx.x; i < len2; i += 256) {
        float2 x = xp[i];
        float2 p = pp[i];
        acc += x.x * p.x + x.y * p.y;
    }
    // wave(64) butterfly reduce
    #pragma unroll
    for (int off = 32; off > 0; off >>= 1)
        acc += __shfl_down(acc, off, 64);

    __shared__ float sacc[4];
    const int lane = threadIdx.x & 63;
    const int w = threadIdx.x >> 6;
    if (lane == 0) sacc[w] = acc;
    __syncthreads();
    if (threadIdx.x == 0)
        part[blockIdx.x] = sacc[0] + sacc[1] + sacc[2] + sacc[3];
}

// ---------------------------------------------------------------------------
// Kernel 3 (per batch b): out[i = k*T + t] = xs[i] * proj[k] * Rx[t]
// Rx[t] reduced from the 16 partials (fixed order -> deterministic) in LDS.
// float4 over t (4 | 64, so k constant within a float4).
// ---------------------------------------------------------------------------
__global__ __launch_bounds__(256) void gate_kernel(
    const float* __restrict__ xs, const float* __restrict__ proj,
    const float* __restrict__ part, float* __restrict__ out, int b)
{
    __shared__ float sRx[T_];
    if (threadIdx.x < T_) {
        float r = 0.f;
        #pragma unroll
        for (int s = 0; s < NSEG; ++s)
            r += part[threadIdx.x * NSEG + s];
        sRx[threadIdx.x] = r;
    }
    __syncthreads();

    unsigned int idx4 = blockIdx.x * 256u + threadIdx.x;    // float4 idx in batch
    const unsigned int N4 = EFT / 4u;                        // 5,179,872
    if (idx4 >= N4) return;
    unsigned int i = idx4 * 4u;                              // element idx in batch
    unsigned int k = i >> 6;
    unsigned int t = i & 63u;

    const float4* __restrict__ xs4 = (const float4*)(xs + (size_t)b * EFT);
    float4* __restrict__ out4 = (float4*)(out + (size_t)b * EFT);

    float p = proj[(size_t)b * EF + k];
    float4 x = xs4[idx4];
    float4 o;
    o.x = x.x * p * sRx[t + 0];
    o.y = x.y * p * sRx[t + 1];
    o.z = x.z * p * sRx[t + 2];
    o.w = x.w * p * sRx[t + 3];
    out4[idx4] = o;
}

extern "C" void kernel_launch(void* const* d_in, const int* in_sizes, int n_in,
                              void* d_out, int out_size, void* d_ws, size_t ws_size,
                              hipStream_t stream)
{
    const float* xs   = (const float*)d_in[0];   // [B,E,F,T]
    const float* xind = (const float*)d_in[1];   // [B,C]
    const float* W    = (const float*)d_in[2];   // [E*F, C]
    const float* bias = (const float*)d_in[3];   // [E*F]

    float* out    = (float*)d_out;                       // [B,E,F,T] flat
    float* anchor = (float*)d_out + (size_t)NOUT;        // [B,F,E] flat == proj
    float* part   = (float*)d_ws;                        // [B][64][16] floats

    // 1) proj -> anchor region (serves as both output and scratch)
    {
        const int n = B_ * EF;                 // 2,589,936
        const int blocks = (n + 255) / 256;    // 10117
        proj_kernel<<<blocks, 256, 0, stream>>>(xind, W, bias, anchor);
    }
    // 2+3) per batch: partial dots, then gate (xs[b] stays L3-resident between)
    const unsigned int gate_blocks = (EFT / 4 + 255) / 256;  // 20234
    for (int b = 0; b < B_; ++b) {
        rx_part_kernel<<<T_ * NSEG, 256, 0, stream>>>(
            xs, anchor, part + b * T_ * NSEG, b);
        gate_kernel<<<gate_blocks, 256, 0, stream>>>(
            xs, anchor, part + b * T_ * NSEG, out, b);
    }
}

// Round 7
// 369.847 us; speedup vs baseline: 1.4661x; 1.1260x over previous
//
#include <hip/hip_runtime.h>

// Problem constants
#define E_ 158
#define F_ 2049
#define T_ 64
#define C_ 2
#define B_ 8
#define EF 323742           // E_*F_
#define EF2 161871          // EF/2 (float2 units per t-chunk)
#define EFT 20719488        // EF*T_ (per-batch element count)
#define NOUT 165755904      // B_*EFT
#define N4TOT 41438976      // NOUT/4 (float4s total); 161871 blocks x 256 exact
#define NSEG 16
#define SEG2 10117          // ceil(EF2/NSEG); last segment = 10116

// ---------------------------------------------------------------------------
// Kernel 1: proj[b,k] = xind[b,0]*W[k,0] + xind[b,1]*W[k,1] + bias[k]
// Written directly into the anchor region of d_out (anchor == proj flat).
// ---------------------------------------------------------------------------
__global__ __launch_bounds__(256) void proj_kernel(
    const float* __restrict__ xind, const float* __restrict__ W,
    const float* __restrict__ bias, float* __restrict__ anchor)
{
    unsigned int idx = blockIdx.x * 256u + threadIdx.x;
    if (idx >= (unsigned int)(B_ * EF)) return;
    unsigned int b = idx / (unsigned int)EF;
    unsigned int k = idx - b * (unsigned int)EF;
    anchor[idx] = xind[b * 2 + 0] * W[2 * k + 0]
                + xind[b * 2 + 1] * W[2 * k + 1]
                + bias[k];
}

// ---------------------------------------------------------------------------
// Kernel 2: partial dots. Block (b,t,s) sums an 81KB contiguous chunk of
// xs_flat[b, t*EF + seg_s] against proj[b, seg_s]. Grid = 8*64*16 = 8192
// blocks (32 blocks/CU of work) -> saturates HBM, unlike round-1's 512.
// ---------------------------------------------------------------------------
__global__ __launch_bounds__(256) void rx_all_kernel(
    const float* __restrict__ xs, const float* __restrict__ proj,
    float* __restrict__ part)
{
    const int blk = blockIdx.x;           // b*1024 + t*16 + s
    const int b = blk >> 10;
    const int t = (blk >> 4) & 63;
    const int s = blk & 15;
    const int len2 = (s == NSEG - 1) ? (EF2 - (NSEG - 1) * SEG2) : SEG2;

    const float2* __restrict__ xp =
        (const float2*)(xs + (size_t)b * EFT) + (size_t)t * EF2 + (size_t)s * SEG2;
    const float2* __restrict__ pp =
        (const float2*)(proj + (size_t)b * EF) + (size_t)s * SEG2;

    float acc = 0.f;
    #pragma unroll 4
    for (int i = threadIdx.x; i < len2; i += 256) {
        float2 x = xp[i];
        float2 p = pp[i];
        acc += x.x * p.x + x.y * p.y;
    }
    #pragma unroll
    for (int off = 32; off > 0; off >>= 1)
        acc += __shfl_down(acc, off, 64);

    __shared__ float sacc[4];
    if ((threadIdx.x & 63) == 0) sacc[threadIdx.x >> 6] = acc;
    __syncthreads();
    if (threadIdx.x == 0)
        part[blk] = sacc[0] + sacc[1] + sacc[2] + sacc[3];
}

// ---------------------------------------------------------------------------
// Kernel 3: Rx[bt] = sum_s part[bt*16+s], one block, fixed order -> bitwise
// deterministic across replays.
// ---------------------------------------------------------------------------
__global__ __launch_bounds__(512) void rx_final_kernel(
    const float* __restrict__ part, float* __restrict__ Rx)
{
    const int bt = threadIdx.x;           // b*64 + t
    float r = 0.f;
    #pragma unroll
    for (int s = 0; s < NSEG; ++s) r += part[bt * NSEG + s];
    Rx[bt] = r;
}

// ---------------------------------------------------------------------------
// Kernel 4: out[i = b*EFT + k*T + t] = xs[i] * proj[b,k] * Rx[b,t], float4
// over t. Blocks walk addresses in REVERSE so the first-processed addresses
// are the ones rx_all streamed last -> still L3-resident (256MB Infinity
// Cache) -> partial HBM fetch saving.
// ---------------------------------------------------------------------------
__global__ __launch_bounds__(256) void gate_all_kernel(
    const float* __restrict__ xs, const float* __restrict__ proj,
    const float* __restrict__ Rx, float* __restrict__ out)
{
    unsigned int rb = (unsigned int)(gridDim.x - 1u - blockIdx.x);
    unsigned int idx4 = rb * 256u + threadIdx.x;   // [0, N4TOT), exact cover
    unsigned int i = idx4 * 4u;
    unsigned int b = i / (unsigned int)EFT;
    unsigned int r = i - b * (unsigned int)EFT;
    unsigned int k = r >> 6;
    unsigned int t = r & 63u;                      // t % 4 == 0

    float p = proj[(size_t)b * EF + k];
    const float4 rx4 = *(const float4*)(Rx + b * T_ + t);
    float4 x = ((const float4*)xs)[idx4];
    float4 o;
    o.x = x.x * p * rx4.x;
    o.y = x.y * p * rx4.y;
    o.z = x.z * p * rx4.z;
    o.w = x.w * p * rx4.w;
    ((float4*)out)[idx4] = o;
}

extern "C" void kernel_launch(void* const* d_in, const int* in_sizes, int n_in,
                              void* d_out, int out_size, void* d_ws, size_t ws_size,
                              hipStream_t stream)
{
    const float* xs   = (const float*)d_in[0];   // [B,E,F,T]
    const float* xind = (const float*)d_in[1];   // [B,C]
    const float* W    = (const float*)d_in[2];   // [E*F, C]
    const float* bias = (const float*)d_in[3];   // [E*F]

    float* out    = (float*)d_out;                    // [B,E,F,T] flat
    float* anchor = (float*)d_out + (size_t)NOUT;     // [B,F,E] flat == proj
    float* part   = (float*)d_ws;                     // [B][64][16] = 8192 f
    float* Rx     = (float*)d_ws + B_ * T_ * NSEG;    // [B][64] = 512 f (16B-aligned)

    // 1) proj -> anchor region (doubles as proj operand)
    {
        const int n = B_ * EF;                        // 2,589,936
        proj_kernel<<<(n + 255) / 256, 256, 0, stream>>>(xind, W, bias, anchor);
    }
    // 2) partial dots: 8192 blocks, each a contiguous 81KB chunk
    rx_all_kernel<<<B_ * T_ * NSEG, 256, 0, stream>>>(xs, anchor, part);
    // 3) finalize Rx (deterministic fixed-order sum)
    rx_final_kernel<<<1, 512, 0, stream>>>(part, Rx);
    // 4) gate, reverse-order for L3 reuse of rx_all's tail
    gate_all_kernel<<<N4TOT / 256, 256, 0, stream>>>(xs, anchor, Rx, out);
}